// Round 1
// baseline (115.555 us; speedup 1.0000x reference)
//
#include <hip/hip_runtime.h>

#define IN_DIM   256
#define OUT_DIM  256
#define NKNOT    19                 // NUM_KNOTS-1 spline segments
#define X_MIN_C  (-5.0f)
#define H_C      (10.0f / 19.0f)
#define INV_H_C  (19.0f / 10.0f)

// ---------------------------------------------------------------------------
// Kernel 1: transpose coeffs [O][I][19][4]f  ->  Ct [(I*19)][O] of float4
// Viewed as float4 matrix A[r=O=256][c=I*19=4864]; we produce B[c][r].
// LDS-tiled 64x64 so both global read and global write are 1KB-coalesced.
// ---------------------------------------------------------------------------
__global__ __launch_bounds__(256) void transpose_coeffs(
        const float4* __restrict__ src, float4* __restrict__ dst) {
    __shared__ float4 tile[64][65];          // +1 pad
    const int c0 = (blockIdx.x % 76) * 64;   // 4864 / 64 = 76 col tiles
    const int r0 = (blockIdx.x / 76) * 64;   // 256 / 64  = 4 row tiles
    const int tx = threadIdx.x & 63;
    const int ty = threadIdx.x >> 6;         // 0..3

    #pragma unroll
    for (int jj = 0; jj < 16; ++jj) {
        const int r = ty * 16 + jj;
        // lanes vary tx -> consecutive c -> coalesced 1KB read
        tile[tx][r] = src[(size_t)(r0 + r) * 4864 + (size_t)(c0 + tx)];
    }
    __syncthreads();
    #pragma unroll
    for (int jj = 0; jj < 16; ++jj) {
        const int c = ty * 16 + jj;
        // lanes vary tx -> consecutive r -> coalesced 1KB write
        dst[(size_t)(c0 + c) * 256 + (size_t)(r0 + tx)] = tile[c][tx];
    }
}

// ---------------------------------------------------------------------------
// Kernel 2: one block per batch element b, one thread per output o.
// Phase 1: 256 threads compute idx[i], t[i] for this b into LDS.
// Phase 2: each thread o accumulates sum_i poly(Ct[i][idx[i]][o], t[i]).
//          Global loads: lane o reads consecutive float4 -> coalesced.
//          LDS reads: all lanes same address -> broadcast (free).
// ---------------------------------------------------------------------------
__global__ __launch_bounds__(256) void kan_main(
        const float*  __restrict__ x,
        const float4* __restrict__ Ct,
        const float*  __restrict__ bias,
        float*        __restrict__ out) {
    __shared__ int   s_koff[IN_DIM];   // idx*256, pre-scaled row offset
    __shared__ float s_t[IN_DIM];

    const int b = blockIdx.x;
    const int o = threadIdx.x;

    {
        const float xv = x[b * IN_DIM + o];
        const float f  = (xv - X_MIN_C) * INV_H_C;
        int idx = (int)floorf(f);
        idx = idx < 0 ? 0 : (idx > NKNOT - 1 ? NKNOT - 1 : idx);
        s_koff[o] = idx * 256;
        s_t[o]    = xv - (X_MIN_C + (float)idx * H_C);
    }
    __syncthreads();

    const float4* base = Ct + o;
    float acc0 = 0.f, acc1 = 0.f, acc2 = 0.f, acc3 = 0.f;

    #pragma unroll 4
    for (int i = 0; i < IN_DIM; i += 4) {
        const float t0 = s_t[i + 0];
        const float t1 = s_t[i + 1];
        const float t2 = s_t[i + 2];
        const float t3 = s_t[i + 3];
        const float4 c0 = base[(i + 0) * (NKNOT * 256) + s_koff[i + 0]];
        const float4 c1 = base[(i + 1) * (NKNOT * 256) + s_koff[i + 1]];
        const float4 c2 = base[(i + 2) * (NKNOT * 256) + s_koff[i + 2]];
        const float4 c3 = base[(i + 3) * (NKNOT * 256) + s_koff[i + 3]];
        acc0 += ((c0.w * t0 + c0.z) * t0 + c0.y) * t0 + c0.x;
        acc1 += ((c1.w * t1 + c1.z) * t1 + c1.y) * t1 + c1.x;
        acc2 += ((c2.w * t2 + c2.z) * t2 + c2.y) * t2 + c2.x;
        acc3 += ((c3.w * t3 + c3.z) * t3 + c3.y) * t3 + c3.x;
    }

    out[b * OUT_DIM + o] = bias[o] + ((acc0 + acc1) + (acc2 + acc3));
}

// ---------------------------------------------------------------------------
extern "C" void kernel_launch(void* const* d_in, const int* in_sizes, int n_in,
                              void* d_out, int out_size, void* d_ws, size_t ws_size,
                              hipStream_t stream) {
    const float* x      = (const float*)d_in[0];   // (B, 256) fp32
    const float* coeffs = (const float*)d_in[1];   // (256, 256, 19, 4) fp32
    const float* bias   = (const float*)d_in[2];   // (256,) fp32
    float*       out    = (float*)d_out;           // (B, 256) fp32

    const int B = in_sizes[0] / IN_DIM;            // 1024
    float4* Ct = (float4*)d_ws;                    // needs 19.9 MB of ws

    transpose_coeffs<<<304, 256, 0, stream>>>((const float4*)coeffs, Ct);
    kan_main<<<B, 256, 0, stream>>>(x, Ct, bias, out);
}

// Round 2
// 106.409 us; speedup vs baseline: 1.0860x; 1.0860x over previous
//
#include <hip/hip_runtime.h>

#define IN_DIM   256
#define OUT_DIM  256
#define NKNOT    19                  // NUM_KNOTS-1 spline segments
#define NCOL     (IN_DIM * NKNOT)    // 4864 "columns" (i,k pairs)
#define X_MIN_C  (-5.0f)
#define H_C      (10.0f / 19.0f)
#define INV_H_C  (19.0f / 10.0f)

// f32 -> bf16 round-to-nearest-even, as raw ushort
__device__ __forceinline__ unsigned short f32_to_bf16(float f) {
    unsigned int u = __float_as_uint(f);
    u += 0x7FFFu + ((u >> 16) & 1u);
    return (unsigned short)(u >> 16);
}
__device__ __forceinline__ float bf16_to_f32(unsigned short h) {
    return __uint_as_float(((unsigned int)h) << 16);
}

// ---------------------------------------------------------------------------
// Kernel 1: transpose + convert
//   coeffs [o=256][c=4864] float4  ->  Ctb [slice=o>>5][c][o&31] ushort4(bf16)
// Slice-major layout: each o-slice of 32 is a contiguous 1.22 MB region so an
// XCD serving one slice keeps it L2-resident.
// ---------------------------------------------------------------------------
__global__ __launch_bounds__(256) void transpose_coeffs(
        const float4* __restrict__ src, ushort4* __restrict__ dst) {
    __shared__ float4 tile[64][65];          // [c_local][o_local], +1 pad
    const int c0 = (blockIdx.x % 76) * 64;   // 4864 / 64 = 76 col tiles
    const int r0 = (blockIdx.x / 76) * 64;   // 256 / 64  = 4 row (o) tiles
    const int tx = threadIdx.x & 63;
    const int ty = threadIdx.x >> 6;         // 0..3

    #pragma unroll
    for (int jj = 0; jj < 16; ++jj) {
        const int r = ty * 16 + jj;
        tile[tx][r] = src[(size_t)(r0 + r) * NCOL + (size_t)(c0 + tx)];
    }
    __syncthreads();
    #pragma unroll
    for (int jj = 0; jj < 16; ++jj) {
        const int c = ty * 16 + jj;          // c_local
        const float4 v = tile[c][tx];
        ushort4 h;
        h.x = f32_to_bf16(v.x); h.y = f32_to_bf16(v.y);
        h.z = f32_to_bf16(v.z); h.w = f32_to_bf16(v.w);
        const int o = r0 + tx;
        // lanes 0-31 and 32-63 each write a contiguous 256B run
        dst[(size_t)(o >> 5) * (NCOL * 32) + (size_t)(c0 + c) * 32 + (o & 31)] = h;
    }
}

// ---------------------------------------------------------------------------
// Kernel 2: block = (b-group of 8) x (o-slice of 32); 256 thr = 32 o x 8 b.
//   blockIdx % 8 = o-slice  -> round-robins onto XCDs; each XCD's coeff
//   working set is one 1.22 MB slice -> L2-resident.
// Phase 1: stage {koff, t} for the 8 batch rows into LDS.
// Phase 2: per i, broadcast {koff,t} from LDS, gather ushort4 (bf16x4)
//          coalesced over o, unpack, Horner, accumulate fp32.
// ---------------------------------------------------------------------------
__global__ __launch_bounds__(256) void kan_main(
        const float*   __restrict__ x,
        const ushort4* __restrict__ Ctb,
        const float*   __restrict__ bias,
        float*         __restrict__ out) {
    __shared__ int2 s_tk[8 * IN_DIM];   // .x = k*32 (elem offset), .y = t bits

    const int s    = blockIdx.x & 7;    // o-slice
    const int bgrp = blockIdx.x >> 3;   // batch group
    const int tid  = threadIdx.x;

    // Phase 1: 8 rows of x, coalesced (i = tid)
    #pragma unroll
    for (int bs = 0; bs < 8; ++bs) {
        const float xv = x[(bgrp * 8 + bs) * IN_DIM + tid];
        const float f  = (xv - X_MIN_C) * INV_H_C;
        int idx = (int)floorf(f);
        idx = idx < 0 ? 0 : (idx > NKNOT - 1 ? NKNOT - 1 : idx);
        s_tk[bs * IN_DIM + tid] =
            make_int2(idx * 32, __float_as_int(xv - (X_MIN_C + (float)idx * H_C)));
    }
    __syncthreads();

    const int o_l = tid & 31;
    const int bs  = tid >> 5;
    const ushort4* base = Ctb + (size_t)s * (NCOL * 32) + o_l;
    const int2* tk = s_tk + bs * IN_DIM;

    float acc0 = 0.f, acc1 = 0.f, acc2 = 0.f, acc3 = 0.f;

    #pragma unroll 4
    for (int i = 0; i < IN_DIM; i += 4) {
        const int2 tk0 = tk[i + 0];
        const int2 tk1 = tk[i + 1];
        const int2 tk2 = tk[i + 2];
        const int2 tk3 = tk[i + 3];
        const ushort4 u0 = base[(i + 0) * (NKNOT * 32) + tk0.x];
        const ushort4 u1 = base[(i + 1) * (NKNOT * 32) + tk1.x];
        const ushort4 u2 = base[(i + 2) * (NKNOT * 32) + tk2.x];
        const ushort4 u3 = base[(i + 3) * (NKNOT * 32) + tk3.x];
        const float t0 = __int_as_float(tk0.y);
        const float t1 = __int_as_float(tk1.y);
        const float t2 = __int_as_float(tk2.y);
        const float t3 = __int_as_float(tk3.y);
        acc0 += ((bf16_to_f32(u0.w) * t0 + bf16_to_f32(u0.z)) * t0 + bf16_to_f32(u0.y)) * t0 + bf16_to_f32(u0.x);
        acc1 += ((bf16_to_f32(u1.w) * t1 + bf16_to_f32(u1.z)) * t1 + bf16_to_f32(u1.y)) * t1 + bf16_to_f32(u1.x);
        acc2 += ((bf16_to_f32(u2.w) * t2 + bf16_to_f32(u2.z)) * t2 + bf16_to_f32(u2.y)) * t2 + bf16_to_f32(u2.x);
        acc3 += ((bf16_to_f32(u3.w) * t3 + bf16_to_f32(u3.z)) * t3 + bf16_to_f32(u3.y)) * t3 + bf16_to_f32(u3.x);
    }

    const int o = s * 32 + o_l;
    out[(bgrp * 8 + bs) * OUT_DIM + o] = bias[o] + ((acc0 + acc1) + (acc2 + acc3));
}

// ---------------------------------------------------------------------------
extern "C" void kernel_launch(void* const* d_in, const int* in_sizes, int n_in,
                              void* d_out, int out_size, void* d_ws, size_t ws_size,
                              hipStream_t stream) {
    const float* x      = (const float*)d_in[0];   // (B, 256) fp32
    const float* coeffs = (const float*)d_in[1];   // (256, 256, 19, 4) fp32
    const float* bias   = (const float*)d_in[2];   // (256,) fp32
    float*       out    = (float*)d_out;           // (B, 256) fp32

    const int B = in_sizes[0] / IN_DIM;            // 1024
    ushort4* Ctb = (ushort4*)d_ws;                 // 9.96 MB of ws

    transpose_coeffs<<<304, 256, 0, stream>>>((const float4*)coeffs, Ctb);
    kan_main<<<B, 256, 0, stream>>>(x, Ctb, bias, out);
}